// Round 18
// baseline (71.728 us; speedup 1.0000x reference)
//
#include <hip/hip_runtime.h>
#include <hip/hip_bf16.h>

// dce_loss: out = concat(centers, sigma, -dist)
// -dist[b,i] = sum_k A[b,k]*W[i,k] + cn[i],  A=[fp8(x^2)|fp8(x)], W=[-sigma|2*sigma*c]
// r18 = r17 (verified 69.6us total / 55.0us gemm / 1250 TF) + T5 setprio(1)
// around the MFMA cluster. Justified: 2 blocks/CU give wave role diversity
// (m218b's prerequisite); r7's null was 1-block lockstep (m190 analog).
// Structure unchanged: fp8, tile 128Mx256N BK=64, grid 512 (2/CU), ring-3
// A (24KB) + ring-3 B (48KB) = 72KB, 1 barrier + 1 counted vmcnt(3)/tile,
// chunk-XOR swizzle (0 conflicts), K-permuted global layout.

#define B_SZ 8192
#define C_SZ 2048
#define D_SZ 1024
#define K2   2048

typedef __attribute__((ext_vector_type(4))) float f32x4;
typedef __attribute__((ext_vector_type(2))) long lx2;

static __device__ __forceinline__ unsigned int pk4(float a, float b, float c, float d) {
  int v = __builtin_amdgcn_cvt_pk_fp8_f32(a, b, 0, false);
  v = __builtin_amdgcn_cvt_pk_fp8_f32(c, d, v, true);
  return (unsigned int)v;
}

// ---- merged preprocess: fp8 A/W with K-permutation (verified r16/r17) -------
__global__ __launch_bounds__(256) void prep(const float* __restrict__ x,
                                            const float* __restrict__ centers,
                                            const float* __restrict__ sigma,
                                            unsigned char* __restrict__ Aop,
                                            float* __restrict__ out_centers,
                                            float* __restrict__ out_sigma,
                                            unsigned char* __restrict__ Wop,
                                            float* __restrict__ cn) {
  if (blockIdx.x < 4096) {
    const long t = (long)blockIdx.x * 256 + threadIdx.x;   // one per 8 elems
    const long e = t * 8;
    const long b = e >> 10;
    const int  d = (int)(e & 1023);
    const float4* xv = (const float4*)x;
    float4 v0 = xv[2 * t], v1 = xv[2 * t + 1];
    float vs[8] = {v0.x, v0.y, v0.z, v0.w, v1.x, v1.y, v1.z, v1.w};
    uint2 sq, rw;
    sq.x = pk4(vs[0]*vs[0], vs[1]*vs[1], vs[2]*vs[2], vs[3]*vs[3]);
    sq.y = pk4(vs[4]*vs[4], vs[5]*vs[5], vs[6]*vs[6], vs[7]*vs[7]);
    rw.x = pk4(vs[0], vs[1], vs[2], vs[3]);
    rw.y = pk4(vs[4], vs[5], vs[6], vs[7]);
    const int m = (d >> 3) & 7;
    const int destc = (d & ~63) + (m < 4 ? m * 16 : (m - 4) * 16 + 8);
    *(uint2*)(Aop + b * K2 + destc)        = sq;
    *(uint2*)(Aop + b * K2 + 1024 + destc) = rw;
  } else {
    const int grp = threadIdx.x >> 7;                        // 0..1
    const int i = (blockIdx.x - 4096) * 2 + grp;             // class
    const int t = threadIdx.x & 127;                         // 0..127
    const long base = (long)i * D_SZ;
    const float4* cv = (const float4*)(centers + base);
    const float4* sv = (const float4*)(sigma + base);
    float4 c0 = cv[2 * t], c1 = cv[2 * t + 1];
    float4 s0 = sv[2 * t], s1 = sv[2 * t + 1];
    ((float4*)(out_centers + base))[2 * t]     = c0;
    ((float4*)(out_centers + base))[2 * t + 1] = c1;
    ((float4*)(out_sigma + base))[2 * t]       = s0;
    ((float4*)(out_sigma + base))[2 * t + 1]   = s1;
    float cs[8] = {c0.x, c0.y, c0.z, c0.w, c1.x, c1.y, c1.z, c1.w};
    float ss[8] = {s0.x, s0.y, s0.z, s0.w, s1.x, s1.y, s1.z, s1.w};
    float p = 0.0f;
#pragma unroll
    for (int j = 0; j < 8; ++j) p += ss[j] * cs[j] * cs[j];
    uint2 w1, w2;
    w1.x = pk4(-ss[0], -ss[1], -ss[2], -ss[3]);
    w1.y = pk4(-ss[4], -ss[5], -ss[6], -ss[7]);
    w2.x = pk4(2.f*ss[0]*cs[0], 2.f*ss[1]*cs[1], 2.f*ss[2]*cs[2], 2.f*ss[3]*cs[3]);
    w2.y = pk4(2.f*ss[4]*cs[4], 2.f*ss[5]*cs[5], 2.f*ss[6]*cs[6], 2.f*ss[7]*cs[7]);
    const int m = t & 7;
    const int destc = (t >> 3) * 64 + (m < 4 ? m * 16 : (m - 4) * 16 + 8);
    *(uint2*)(Wop + (long)i * K2 + destc)        = w1;
    *(uint2*)(Wop + (long)i * K2 + 1024 + destc) = w2;
#pragma unroll
    for (int off = 32; off > 0; off >>= 1) p += __shfl_down(p, off, 64);
    __shared__ float red[2][2];
    if ((t & 63) == 0) red[grp][t >> 6] = p;
    __syncthreads();
    if (t == 0) cn[i] = -(red[grp][0] + red[grp][1]);
  }
}

// ---- GEMM -------------------------------------------------------------------
#define VM3()  asm volatile("s_waitcnt vmcnt(3)" ::: "memory")
#define VM0()  asm volatile("s_waitcnt vmcnt(0)" ::: "memory")
#define NOW()  ((void)0)
#define SB()   __builtin_amdgcn_sched_barrier(0)
#define BAR()  __builtin_amdgcn_s_barrier()

// stage A tile KT (128x64B = 8KB, 1 load) into buf C
#define STAGE_A(C, KT)                                                          \
  __builtin_amdgcn_global_load_lds(                                             \
      (__attribute__((address_space(1))) void*)(aS + (long)(KT) * 64),          \
      (__attribute__((address_space(3))) void*)(&As[C][tid * 16]), 16, 0, 0)

// stage B tile KT (256x64B = 16KB, 2 loads) into buf C
#define STAGE_B(C, KT)                                                          \
  do {                                                                          \
    __builtin_amdgcn_global_load_lds(                                           \
        (__attribute__((address_space(1))) void*)(bS + (long)(KT) * 64),        \
        (__attribute__((address_space(3))) void*)(&Bs[C][tid * 16]), 16, 0, 0); \
    __builtin_amdgcn_global_load_lds(                                           \
        (__attribute__((address_space(1))) void*)(bS + 128 * (long)K2 + (long)(KT) * 64), \
        (__attribute__((address_space(3))) void*)(&Bs[C][8192 + tid * 16]), 16, 0, 0);    \
  } while (0)

// One K-tile U from bufs BUF (=U%3); stage U+2 -> SBUF (=(U+2)%3).
// Reads 8 b128 frags (each 16B = both k-halves), setprio(1) 32 MFMA setprio(0),
// 1 counted vmcnt, 1 barrier.
#define TILE(BUF, SBUF, U, DOST, W)                                            \
  {                                                                            \
    if (DOST) { STAGE_A(SBUF, (U) + 2); STAGE_B(SBUF, (U) + 2); }              \
    lx2 a0 = *(const lx2*)(&As[BUF][aBase +    0]);                            \
    lx2 a1 = *(const lx2*)(&As[BUF][aBase + 1024]);                            \
    lx2 a2 = *(const lx2*)(&As[BUF][aBase + 2048]);                            \
    lx2 a3 = *(const lx2*)(&As[BUF][aBase + 3072]);                            \
    lx2 b0 = *(const lx2*)(&Bs[BUF][bBase +    0]);                            \
    lx2 b1 = *(const lx2*)(&Bs[BUF][bBase + 1024]);                            \
    lx2 b2 = *(const lx2*)(&Bs[BUF][bBase + 2048]);                            \
    lx2 b3 = *(const lx2*)(&Bs[BUF][bBase + 3072]);                            \
    __builtin_amdgcn_s_setprio(1);                                             \
    _Pragma("unroll") for (int mi_ = 0; mi_ < 4; ++mi_) {                      \
      lx2 am = (mi_ == 0) ? a0 : (mi_ == 1) ? a1 : (mi_ == 2) ? a2 : a3;       \
      acc[mi_][0] = __builtin_amdgcn_mfma_f32_16x16x32_fp8_fp8(am.x, b0.x, acc[mi_][0], 0,0,0); \
      acc[mi_][1] = __builtin_amdgcn_mfma_f32_16x16x32_fp8_fp8(am.x, b1.x, acc[mi_][1], 0,0,0); \
      acc[mi_][2] = __builtin_amdgcn_mfma_f32_16x16x32_fp8_fp8(am.x, b2.x, acc[mi_][2], 0,0,0); \
      acc[mi_][3] = __builtin_amdgcn_mfma_f32_16x16x32_fp8_fp8(am.x, b3.x, acc[mi_][3], 0,0,0); \
    }                                                                          \
    _Pragma("unroll") for (int mi_ = 0; mi_ < 4; ++mi_) {                      \
      lx2 am = (mi_ == 0) ? a0 : (mi_ == 1) ? a1 : (mi_ == 2) ? a2 : a3;       \
      acc[mi_][0] = __builtin_amdgcn_mfma_f32_16x16x32_fp8_fp8(am.y, b0.y, acc[mi_][0], 0,0,0); \
      acc[mi_][1] = __builtin_amdgcn_mfma_f32_16x16x32_fp8_fp8(am.y, b1.y, acc[mi_][1], 0,0,0); \
      acc[mi_][2] = __builtin_amdgcn_mfma_f32_16x16x32_fp8_fp8(am.y, b2.y, acc[mi_][2], 0,0,0); \
      acc[mi_][3] = __builtin_amdgcn_mfma_f32_16x16x32_fp8_fp8(am.y, b3.y, acc[mi_][3], 0,0,0); \
    }                                                                          \
    __builtin_amdgcn_s_setprio(0);                                             \
    SB(); W(); SB(); BAR();                                                    \
  }

__global__ __launch_bounds__(512, 4) void gemm256(const unsigned char* __restrict__ A,
                                                  const unsigned char* __restrict__ W,
                                                  const float* __restrict__ cn,
                                                  float* __restrict__ out) {
  // A: ring-3 [3][128 rows][64B] = 24KB; B: ring-3 [3][256][64B] = 48KB. 72KB.
  __shared__ __attribute__((aligned(16))) unsigned char As[3][8192];
  __shared__ __attribute__((aligned(16))) unsigned char Bs[3][16384];

  const int tid  = threadIdx.x;
  const int lane = tid & 63;
  const int wave = tid >> 6;
  const int wr = wave >> 2;              // 0..1 -> 64-row half of M (128 tile)
  const int wc = wave & 3;               // 0..3 -> 64-col slice of N (256 tile)

  // XCD swizzle: 512 blocks = 8 xcd x (8 m x 8 n)
  const int bid = blockIdx.x;
  const int xcd = bid & 7, idx = bid >> 3;             // idx 0..63
  const long rowBase = (long)(xcd * 8 + (idx >> 3)) * 128;
  const long colBase = (long)(idx & 7) * 256;

  // staging: row = tid>>2 (+128 for B half 1); phys chunk tid&3 holds logical
  // chunk (tid&3)^((row>>1)&3)
  const int sl = (tid & 3) ^ ((tid >> 3) & 3);
  const unsigned char* aS = A + (rowBase + (tid >> 2)) * (long)K2 + sl * 16;
  const unsigned char* bS = W + (colBase + (tid >> 2)) * (long)K2 + sl * 16;

  // fragment reads: row = w*64 + mi*16 + l15; phys chunk = q ^ ((l15>>1)&3)
  const int l15 = lane & 15, q = lane >> 4;
  const int ck = (q ^ ((l15 >> 1) & 3)) * 16;
  const int aBase = (wr * 64 + l15) * 64 + ck;
  const int bBase = (wc * 64 + l15) * 64 + ck;

  f32x4 acc[4][4];
#pragma unroll
  for (int i = 0; i < 4; ++i)
#pragma unroll
    for (int j = 0; j < 4; ++j) acc[i][j] = (f32x4){0.f, 0.f, 0.f, 0.f};

  // prologue: A0,B0 -> buf0; A1,B1 -> buf1. FIFO [A0,B0x2,A1,B1x2]=6.
  STAGE_A(0, 0); STAGE_B(0, 0);
  STAGE_A(1, 1); STAGE_B(1, 1);
  VM3(); SB(); BAR();

  // tiles 0..29 (period 3): read buf u%3, stage (u+2)%3; VM3 proves next tile.
#pragma unroll 1
  for (int u = 0; u < 30; u += 3) {
    TILE(0, 2, u + 0, 1, VM3);
    TILE(1, 0, u + 1, 1, VM3);
    TILE(2, 1, u + 2, 1, VM3);
  }
  TILE(0, 0, 30, 0, VM0);   // drain: tile-31 operands land
  TILE(1, 0, 31, 0, NOW);

  // epilogue: C/D layout col=lane&15, row=(lane>>4)*4+j (shape-determined)
  const int crow = (lane >> 4) * 4;
  const int ccol = lane & 15;
#pragma unroll
  for (int ni = 0; ni < 4; ++ni) {
    const long col = colBase + wc * 64 + ni * 16 + ccol;
    const float c = cn[col];
#pragma unroll
    for (int mi = 0; mi < 4; ++mi) {
      const long row = rowBase + wr * 64 + mi * 16 + crow;
      float* o = out + row * C_SZ + col;
#pragma unroll
      for (int j = 0; j < 4; ++j) o[(long)j * C_SZ] = acc[mi][ni][j] + c;
    }
  }
}

extern "C" void kernel_launch(void* const* d_in, const int* in_sizes, int n_in,
                              void* d_out, int out_size, void* d_ws, size_t ws_size,
                              hipStream_t stream) {
  const float* x       = (const float*)d_in[0];
  const float* centers = (const float*)d_in[1];
  const float* sigma   = (const float*)d_in[2];
  float* out = (float*)d_out;

  unsigned char* Aop = (unsigned char*)d_ws;              // 8192*2048 fp8 = 16MB
  unsigned char* Wop = Aop + (long)B_SZ * K2;             // 2048*2048 fp8 = 4MB
  float* cnp = (float*)(Wop + (long)C_SZ * K2);           // 2048 f32

  prep<<<4096 + 1024, 256, 0, stream>>>(x, centers, sigma, Aop,
                                        out, out + (size_t)C_SZ * D_SZ, Wop, cnp);

  float* out2 = out + (size_t)2 * C_SZ * D_SZ;
  gemm256<<<512, 512, 0, stream>>>(Aop, Wop, cnp, out2);
}

// Round 19
// 69.724 us; speedup vs baseline: 1.0287x; 1.0287x over previous
//
#include <hip/hip_runtime.h>
#include <hip/hip_bf16.h>

// dce_loss: out = concat(centers, sigma, -dist)
// -dist[b,i] = sum_k A[b,k]*W[i,k] + cn[i],  A=[fp8(x^2)|fp8(x)], W=[-sigma|2*sigma*c]
// SESSION-BEST r17 (verified 69.6us total / 55.0us gemm / 1250 TF / MfmaUtil 48%):
// fp8 e4m3 operands (sigma==1 exact; quant err << thr). Tile 128Mx256N BK=64,
// grid 512 = 2 BLOCKS/CU (the decisive lever: cross-block TLP absorbs sync
// stalls). Ring-3 A (24KB) + ring-3 B (48KB) = 72KB LDS. Fragments (16B =
// both k-halves) read once per tile -> 1 barrier + 1 counted vmcnt(3)/tile.
// Chunk-XOR swizzle (0 conflicts). K-permuted global layout from prep.
// r18 showed setprio REGRESSES here (inter-block balance beats priority) —
// reverted. All other levers measured worse r1-r16.

#define B_SZ 8192
#define C_SZ 2048
#define D_SZ 1024
#define K2   2048

typedef __attribute__((ext_vector_type(4))) float f32x4;
typedef __attribute__((ext_vector_type(2))) long lx2;

static __device__ __forceinline__ unsigned int pk4(float a, float b, float c, float d) {
  int v = __builtin_amdgcn_cvt_pk_fp8_f32(a, b, 0, false);
  v = __builtin_amdgcn_cvt_pk_fp8_f32(c, d, v, true);
  return (unsigned int)v;
}

// ---- merged preprocess: fp8 A/W with K-permutation (verified r16/r17) -------
__global__ __launch_bounds__(256) void prep(const float* __restrict__ x,
                                            const float* __restrict__ centers,
                                            const float* __restrict__ sigma,
                                            unsigned char* __restrict__ Aop,
                                            float* __restrict__ out_centers,
                                            float* __restrict__ out_sigma,
                                            unsigned char* __restrict__ Wop,
                                            float* __restrict__ cn) {
  if (blockIdx.x < 4096) {
    const long t = (long)blockIdx.x * 256 + threadIdx.x;   // one per 8 elems
    const long e = t * 8;
    const long b = e >> 10;
    const int  d = (int)(e & 1023);
    const float4* xv = (const float4*)x;
    float4 v0 = xv[2 * t], v1 = xv[2 * t + 1];
    float vs[8] = {v0.x, v0.y, v0.z, v0.w, v1.x, v1.y, v1.z, v1.w};
    uint2 sq, rw;
    sq.x = pk4(vs[0]*vs[0], vs[1]*vs[1], vs[2]*vs[2], vs[3]*vs[3]);
    sq.y = pk4(vs[4]*vs[4], vs[5]*vs[5], vs[6]*vs[6], vs[7]*vs[7]);
    rw.x = pk4(vs[0], vs[1], vs[2], vs[3]);
    rw.y = pk4(vs[4], vs[5], vs[6], vs[7]);
    const int m = (d >> 3) & 7;
    const int destc = (d & ~63) + (m < 4 ? m * 16 : (m - 4) * 16 + 8);
    *(uint2*)(Aop + b * K2 + destc)        = sq;
    *(uint2*)(Aop + b * K2 + 1024 + destc) = rw;
  } else {
    const int grp = threadIdx.x >> 7;                        // 0..1
    const int i = (blockIdx.x - 4096) * 2 + grp;             // class
    const int t = threadIdx.x & 127;                         // 0..127
    const long base = (long)i * D_SZ;
    const float4* cv = (const float4*)(centers + base);
    const float4* sv = (const float4*)(sigma + base);
    float4 c0 = cv[2 * t], c1 = cv[2 * t + 1];
    float4 s0 = sv[2 * t], s1 = sv[2 * t + 1];
    ((float4*)(out_centers + base))[2 * t]     = c0;
    ((float4*)(out_centers + base))[2 * t + 1] = c1;
    ((float4*)(out_sigma + base))[2 * t]       = s0;
    ((float4*)(out_sigma + base))[2 * t + 1]   = s1;
    float cs[8] = {c0.x, c0.y, c0.z, c0.w, c1.x, c1.y, c1.z, c1.w};
    float ss[8] = {s0.x, s0.y, s0.z, s0.w, s1.x, s1.y, s1.z, s1.w};
    float p = 0.0f;
#pragma unroll
    for (int j = 0; j < 8; ++j) p += ss[j] * cs[j] * cs[j];
    uint2 w1, w2;
    w1.x = pk4(-ss[0], -ss[1], -ss[2], -ss[3]);
    w1.y = pk4(-ss[4], -ss[5], -ss[6], -ss[7]);
    w2.x = pk4(2.f*ss[0]*cs[0], 2.f*ss[1]*cs[1], 2.f*ss[2]*cs[2], 2.f*ss[3]*cs[3]);
    w2.y = pk4(2.f*ss[4]*cs[4], 2.f*ss[5]*cs[5], 2.f*ss[6]*cs[6], 2.f*ss[7]*cs[7]);
    const int m = t & 7;
    const int destc = (t >> 3) * 64 + (m < 4 ? m * 16 : (m - 4) * 16 + 8);
    *(uint2*)(Wop + (long)i * K2 + destc)        = w1;
    *(uint2*)(Wop + (long)i * K2 + 1024 + destc) = w2;
#pragma unroll
    for (int off = 32; off > 0; off >>= 1) p += __shfl_down(p, off, 64);
    __shared__ float red[2][2];
    if ((t & 63) == 0) red[grp][t >> 6] = p;
    __syncthreads();
    if (t == 0) cn[i] = -(red[grp][0] + red[grp][1]);
  }
}

// ---- GEMM -------------------------------------------------------------------
#define VM3()  asm volatile("s_waitcnt vmcnt(3)" ::: "memory")
#define VM0()  asm volatile("s_waitcnt vmcnt(0)" ::: "memory")
#define NOW()  ((void)0)
#define SB()   __builtin_amdgcn_sched_barrier(0)
#define BAR()  __builtin_amdgcn_s_barrier()

// stage A tile KT (128x64B = 8KB, 1 load) into buf C
#define STAGE_A(C, KT)                                                          \
  __builtin_amdgcn_global_load_lds(                                             \
      (__attribute__((address_space(1))) void*)(aS + (long)(KT) * 64),          \
      (__attribute__((address_space(3))) void*)(&As[C][tid * 16]), 16, 0, 0)

// stage B tile KT (256x64B = 16KB, 2 loads) into buf C
#define STAGE_B(C, KT)                                                          \
  do {                                                                          \
    __builtin_amdgcn_global_load_lds(                                           \
        (__attribute__((address_space(1))) void*)(bS + (long)(KT) * 64),        \
        (__attribute__((address_space(3))) void*)(&Bs[C][tid * 16]), 16, 0, 0); \
    __builtin_amdgcn_global_load_lds(                                           \
        (__attribute__((address_space(1))) void*)(bS + 128 * (long)K2 + (long)(KT) * 64), \
        (__attribute__((address_space(3))) void*)(&Bs[C][8192 + tid * 16]), 16, 0, 0);    \
  } while (0)

// One K-tile U from bufs BUF (=U%3); stage U+2 -> SBUF (=(U+2)%3).
// Reads 8 b128 frags (each 16B = both k-halves), 32 MFMA, 1 vmcnt, 1 barrier.
#define TILE(BUF, SBUF, U, DOST, W)                                            \
  {                                                                            \
    if (DOST) { STAGE_A(SBUF, (U) + 2); STAGE_B(SBUF, (U) + 2); }              \
    lx2 a0 = *(const lx2*)(&As[BUF][aBase +    0]);                            \
    lx2 a1 = *(const lx2*)(&As[BUF][aBase + 1024]);                            \
    lx2 a2 = *(const lx2*)(&As[BUF][aBase + 2048]);                            \
    lx2 a3 = *(const lx2*)(&As[BUF][aBase + 3072]);                            \
    lx2 b0 = *(const lx2*)(&Bs[BUF][bBase +    0]);                            \
    lx2 b1 = *(const lx2*)(&Bs[BUF][bBase + 1024]);                            \
    lx2 b2 = *(const lx2*)(&Bs[BUF][bBase + 2048]);                            \
    lx2 b3 = *(const lx2*)(&Bs[BUF][bBase + 3072]);                            \
    _Pragma("unroll") for (int mi_ = 0; mi_ < 4; ++mi_) {                      \
      lx2 am = (mi_ == 0) ? a0 : (mi_ == 1) ? a1 : (mi_ == 2) ? a2 : a3;       \
      acc[mi_][0] = __builtin_amdgcn_mfma_f32_16x16x32_fp8_fp8(am.x, b0.x, acc[mi_][0], 0,0,0); \
      acc[mi_][1] = __builtin_amdgcn_mfma_f32_16x16x32_fp8_fp8(am.x, b1.x, acc[mi_][1], 0,0,0); \
      acc[mi_][2] = __builtin_amdgcn_mfma_f32_16x16x32_fp8_fp8(am.x, b2.x, acc[mi_][2], 0,0,0); \
      acc[mi_][3] = __builtin_amdgcn_mfma_f32_16x16x32_fp8_fp8(am.x, b3.x, acc[mi_][3], 0,0,0); \
    }                                                                          \
    _Pragma("unroll") for (int mi_ = 0; mi_ < 4; ++mi_) {                      \
      lx2 am = (mi_ == 0) ? a0 : (mi_ == 1) ? a1 : (mi_ == 2) ? a2 : a3;       \
      acc[mi_][0] = __builtin_amdgcn_mfma_f32_16x16x32_fp8_fp8(am.y, b0.y, acc[mi_][0], 0,0,0); \
      acc[mi_][1] = __builtin_amdgcn_mfma_f32_16x16x32_fp8_fp8(am.y, b1.y, acc[mi_][1], 0,0,0); \
      acc[mi_][2] = __builtin_amdgcn_mfma_f32_16x16x32_fp8_fp8(am.y, b2.y, acc[mi_][2], 0,0,0); \
      acc[mi_][3] = __builtin_amdgcn_mfma_f32_16x16x32_fp8_fp8(am.y, b3.y, acc[mi_][3], 0,0,0); \
    }                                                                          \
    SB(); W(); SB(); BAR();                                                    \
  }

__global__ __launch_bounds__(512, 4) void gemm256(const unsigned char* __restrict__ A,
                                                  const unsigned char* __restrict__ W,
                                                  const float* __restrict__ cn,
                                                  float* __restrict__ out) {
  // A: ring-3 [3][128 rows][64B] = 24KB; B: ring-3 [3][256][64B] = 48KB. 72KB.
  __shared__ __attribute__((aligned(16))) unsigned char As[3][8192];
  __shared__ __attribute__((aligned(16))) unsigned char Bs[3][16384];

  const int tid  = threadIdx.x;
  const int lane = tid & 63;
  const int wave = tid >> 6;
  const int wr = wave >> 2;              // 0..1 -> 64-row half of M (128 tile)
  const int wc = wave & 3;               // 0..3 -> 64-col slice of N (256 tile)

  // XCD swizzle: 512 blocks = 8 xcd x (8 m x 8 n)
  const int bid = blockIdx.x;
  const int xcd = bid & 7, idx = bid >> 3;             // idx 0..63
  const long rowBase = (long)(xcd * 8 + (idx >> 3)) * 128;
  const long colBase = (long)(idx & 7) * 256;

  // staging: row = tid>>2 (+128 for B half 1); phys chunk tid&3 holds logical
  // chunk (tid&3)^((row>>1)&3)
  const int sl = (tid & 3) ^ ((tid >> 3) & 3);
  const unsigned char* aS = A + (rowBase + (tid >> 2)) * (long)K2 + sl * 16;
  const unsigned char* bS = W + (colBase + (tid >> 2)) * (long)K2 + sl * 16;

  // fragment reads: row = w*64 + mi*16 + l15; phys chunk = q ^ ((l15>>1)&3)
  const int l15 = lane & 15, q = lane >> 4;
  const int ck = (q ^ ((l15 >> 1) & 3)) * 16;
  const int aBase = (wr * 64 + l15) * 64 + ck;
  const int bBase = (wc * 64 + l15) * 64 + ck;

  f32x4 acc[4][4];
#pragma unroll
  for (int i = 0; i < 4; ++i)
#pragma unroll
    for (int j = 0; j < 4; ++j) acc[i][j] = (f32x4){0.f, 0.f, 0.f, 0.f};

  // prologue: A0,B0 -> buf0; A1,B1 -> buf1. FIFO [A0,B0x2,A1,B1x2]=6.
  // VM3 proves A0,B0x2; leaves [A1,B1x2] = the steady invariant.
  STAGE_A(0, 0); STAGE_B(0, 0);
  STAGE_A(1, 1); STAGE_B(1, 1);
  VM3(); SB(); BAR();

  // tiles 0..29 (period 3): read buf u%3, stage (u+2)%3; VM3 proves next tile.
#pragma unroll 1
  for (int u = 0; u < 30; u += 3) {
    TILE(0, 2, u + 0, 1, VM3);
    TILE(1, 0, u + 1, 1, VM3);
    TILE(2, 1, u + 2, 1, VM3);
  }
  TILE(0, 0, 30, 0, VM0);   // drain: tile-31 operands land
  TILE(1, 0, 31, 0, NOW);

  // epilogue: C/D layout col=lane&15, row=(lane>>4)*4+j (shape-determined)
  const int crow = (lane >> 4) * 4;
  const int ccol = lane & 15;
#pragma unroll
  for (int ni = 0; ni < 4; ++ni) {
    const long col = colBase + wc * 64 + ni * 16 + ccol;
    const float c = cn[col];
#pragma unroll
    for (int mi = 0; mi < 4; ++mi) {
      const long row = rowBase + wr * 64 + mi * 16 + crow;
      float* o = out + row * C_SZ + col;
#pragma unroll
      for (int j = 0; j < 4; ++j) o[(long)j * C_SZ] = acc[mi][ni][j] + c;
    }
  }
}

extern "C" void kernel_launch(void* const* d_in, const int* in_sizes, int n_in,
                              void* d_out, int out_size, void* d_ws, size_t ws_size,
                              hipStream_t stream) {
  const float* x       = (const float*)d_in[0];
  const float* centers = (const float*)d_in[1];
  const float* sigma   = (const float*)d_in[2];
  float* out = (float*)d_out;

  unsigned char* Aop = (unsigned char*)d_ws;              // 8192*2048 fp8 = 16MB
  unsigned char* Wop = Aop + (long)B_SZ * K2;             // 2048*2048 fp8 = 4MB
  float* cnp = (float*)(Wop + (long)C_SZ * K2);           // 2048 f32

  prep<<<4096 + 1024, 256, 0, stream>>>(x, centers, sigma, Aop,
                                        out, out + (size_t)C_SZ * D_SZ, Wop, cnp);

  float* out2 = out + (size_t)2 * C_SZ * D_SZ;
  gemm256<<<512, 512, 0, stream>>>(Aop, Wop, cnp, out2);
}